// Round 1
// baseline (9855.634 us; speedup 1.0000x reference)
//
#include <hip/hip_runtime.h>
#include <math.h>

#define BB   8
#define TT   64
#define NN   256
#define HH   256
#define BN   2048   // BB*NN

// ---------------------------------------------------------------------------
// Generic 64x64-tile fp32 GEMM accumulation over K=256.
// A-operand: Arows[i*lda + k]  (64 rows of the tile, K contiguous)
// B-operand: Bcols[k*ldb + j]  (K rows, 64 cols of the tile)
// LDS: As stored transposed [k][i] so the inner loop is 2x ds_read_b128.
// ---------------------------------------------------------------------------
__device__ __forceinline__ void gemm_k256(float acc[4][4],
    const float* __restrict__ Arows, int lda,
    const float* __restrict__ Bcols, int ldb,
    float (*As)[68], float (*Bs)[68], int tid)
{
    const int tx = tid & 15, ty = tid >> 4;
    for (int k0 = 0; k0 < 256; k0 += 32) {
        __syncthreads();   // protect LDS reuse across chunks / calls
        {
            int i  = tid >> 2;
            int kw = (tid & 3) << 3;
            const float* s = Arows + i * lda + k0 + kw;
            float4 a0 = *(const float4*)s;
            float4 a1 = *(const float4*)(s + 4);
            As[kw+0][i] = a0.x; As[kw+1][i] = a0.y; As[kw+2][i] = a0.z; As[kw+3][i] = a0.w;
            As[kw+4][i] = a1.x; As[kw+5][i] = a1.y; As[kw+6][i] = a1.z; As[kw+7][i] = a1.w;

            int kb = tid >> 3;
            int j  = (tid & 7) << 3;
            const float* bsrc = Bcols + (size_t)(k0 + kb) * ldb + j;
            float4 b0 = *(const float4*)bsrc;
            float4 b1 = *(const float4*)(bsrc + 4);
            *(float4*)&Bs[kb][j]     = b0;
            *(float4*)&Bs[kb][j + 4] = b1;
        }
        __syncthreads();
        #pragma unroll
        for (int kk = 0; kk < 32; ++kk) {
            float4 av = *(const float4*)&As[kk][ty << 2];
            float4 bv = *(const float4*)&Bs[kk][tx << 2];
            acc[0][0] = fmaf(av.x, bv.x, acc[0][0]);
            acc[0][1] = fmaf(av.x, bv.y, acc[0][1]);
            acc[0][2] = fmaf(av.x, bv.z, acc[0][2]);
            acc[0][3] = fmaf(av.x, bv.w, acc[0][3]);
            acc[1][0] = fmaf(av.y, bv.x, acc[1][0]);
            acc[1][1] = fmaf(av.y, bv.y, acc[1][1]);
            acc[1][2] = fmaf(av.y, bv.z, acc[1][2]);
            acc[1][3] = fmaf(av.y, bv.w, acc[1][3]);
            acc[2][0] = fmaf(av.z, bv.x, acc[2][0]);
            acc[2][1] = fmaf(av.z, bv.y, acc[2][1]);
            acc[2][2] = fmaf(av.z, bv.z, acc[2][2]);
            acc[2][3] = fmaf(av.z, bv.w, acc[2][3]);
            acc[3][0] = fmaf(av.w, bv.x, acc[3][0]);
            acc[3][1] = fmaf(av.w, bv.y, acc[3][1]);
            acc[3][2] = fmaf(av.w, bv.z, acc[3][2]);
            acc[3][3] = fmaf(av.w, bv.w, acc[3][3]);
        }
    }
}

// ---------------------------------------------------------------------------
// G1: batched A-apply  Y[b*256+n, :] = sum_m A[n,m] X[b*256+m, :]
// Up to 2 jobs (128 blocks each) + optional x-job: Ax0 = A @ (x_t * mask_t)
// ---------------------------------------------------------------------------
struct G1P {
    const float* A;
    const float* X0; float* Y0;
    const float* X1; float* Y1;
    int nJobs;
    int withX;
    int t;
    const float* x2d;
    const float* mask;
    float* Ax0;   // [2048][8] (stride 8, cols 0..5 valid)
};

__global__ __launch_bounds__(256) void g1_kernel(G1P p) {
    __shared__ float As[32][68];
    __shared__ float Bs[32][68];
    const int tid = threadIdx.x;
    const int bid = blockIdx.x;
    const int mainBlocks = p.nJobs * 128;

    if (bid < mainBlocks) {
        int job = bid >> 7;
        int lb  = bid & 127;
        const float* X = job ? p.X1 : p.X0;
        float*       Y = job ? p.Y1 : p.Y0;
        int b  = lb >> 4;
        int rt = (lb >> 2) & 3;
        int ct = lb & 3;
        float acc[4][4] = {{0.f}};
        gemm_k256(acc, p.A + rt * 64 * 256, 256,
                  X + b * 65536 + ct * 64, 256, As, Bs, tid);
        int tx = tid & 15, ty = tid >> 4;
        float* yb = Y + (size_t)(b * 256 + rt * 64 + ty * 4) * 256 + ct * 64 + tx * 4;
        #pragma unroll
        for (int r = 0; r < 4; ++r) {
            float4 v; v.x = acc[r][0]; v.y = acc[r][1]; v.z = acc[r][2]; v.w = acc[r][3];
            *(float4*)(yb + (size_t)r * 256) = v;
        }
    } else {
        // x-job: 32 blocks, each 64 rows of Ax0 = A @ (x_t * mask_t)
        int lb = bid - mainBlocks;          // 0..31
        int b  = lb >> 2;
        int rt = lb & 3;
        float* xs  = &As[0][0];             // view [256][8]  (2048 floats)
        float* red = &Bs[0][0];             // view [64][4][8]
        const float* xbase = p.x2d  + ((size_t)(b * TT + p.t) * NN) * 6;
        const float* mbase = p.mask + (size_t)(b * TT + p.t) * NN;
        {
            int m = tid;                    // 0..255
            float mk = mbase[m];
            #pragma unroll
            for (int d = 0; d < 6; ++d) xs[m * 8 + d] = xbase[m * 6 + d] * mk;
        }
        __syncthreads();
        int i = tid & 63, q = tid >> 6;     // lane-contiguous rows
        const float* arow = p.A + (size_t)(rt * 64 + i) * 256 + q * 64;
        float a6[6] = {0.f, 0.f, 0.f, 0.f, 0.f, 0.f};
        for (int m = 0; m < 64; ++m) {
            float a = arow[m];
            const float* xv = &xs[(q * 64 + m) * 8];
            #pragma unroll
            for (int d = 0; d < 6; ++d) a6[d] = fmaf(a, xv[d], a6[d]);
        }
        #pragma unroll
        for (int d = 0; d < 6; ++d) red[(i * 4 + q) * 8 + d] = a6[d];
        __syncthreads();
        for (int idx = tid; idx < 64 * 6; idx += 256) {
            int ii = idx / 6, d = idx - ii * 6;
            float s = red[(ii * 4 + 0) * 8 + d] + red[(ii * 4 + 1) * 8 + d]
                    + red[(ii * 4 + 2) * 8 + d] + red[(ii * 4 + 3) * 8 + d];
            p.Ax0[(size_t)(b * 256 + rt * 64 + ii) * 8 + d] = s;
        }
    }
}

// ---------------------------------------------------------------------------
// WAct: g = bias[j] + X1@W1[:,j] + X2@W2[:,j], then gate epilogue.
//   mode 0 (ZR, 512 cols): z = sigmoid(g[:,:256]); rh = sigmoid(g[:,256:])*h
//   mode 1 (C, 256 cols):  c = tanh(g); h = z*h + (1-z)*c   (in-place)
// K2 == 6 means X2 is Ax0 (stride 8); else K2 == 256 (stride 256).
// All W matrices have row stride 768; pass W pointers pre-offset by column.
// ---------------------------------------------------------------------------
struct WAP {
    const float* X1; const float* W1;
    const float* X2; const float* W2;
    int K2;
    const float* bias;
    const float* h; float* z; float* rh;   // ZR mode
    const float* zin; float* hio;          // C mode
    int mode;                               // 0 = ZR (8 col tiles), 1 = C (4)
};

__global__ __launch_bounds__(256) void wact_kernel(WAP p) {
    __shared__ float As[32][68];
    __shared__ float Bs[32][68];
    __shared__ float X2s[64][8];
    __shared__ float W2s[8][68];
    const int tid = threadIdx.x;
    const int bid = blockIdx.x;
    const int nct = p.mode ? 4 : 8;
    int b  = bid / (4 * nct);
    int r2 = bid % (4 * nct);
    int rt = r2 / nct;
    int ct = r2 % nct;
    int row0 = b * 256 + rt * 64;

    float acc[4][4] = {{0.f}};
    gemm_k256(acc, p.X1 + (size_t)row0 * 256, 256, p.W1 + ct * 64, 768, As, Bs, tid);

    if (p.K2 == 256) {
        gemm_k256(acc, p.X2 + (size_t)row0 * 256, 256, p.W2 + ct * 64, 768, As, Bs, tid);
    } else {
        // K2 == 6: small epilogue GEMM from Ax0 (stride 8) and 6 rows of W2
        __syncthreads();
        if (tid < 128) {
            int i  = tid >> 1;
            int d4 = (tid & 1) * 4;
            *(float4*)&X2s[i][d4] = *(const float4*)(p.X2 + (size_t)(row0 + i) * 8 + d4);
        } else {
            int t2 = tid - 128;
            for (int idx = t2; idx < 384; idx += 128) {
                int d = idx >> 6, j = idx & 63;
                W2s[d][j] = p.W2[(size_t)d * 768 + ct * 64 + j];
            }
        }
        __syncthreads();
        int tx = tid & 15, ty = tid >> 4;
        #pragma unroll
        for (int d = 0; d < 6; ++d) {
            float4 bv = *(const float4*)&W2s[d][tx << 2];
            float a0 = X2s[ty * 4 + 0][d];
            float a1 = X2s[ty * 4 + 1][d];
            float a2 = X2s[ty * 4 + 2][d];
            float a3 = X2s[ty * 4 + 3][d];
            acc[0][0] = fmaf(a0, bv.x, acc[0][0]); acc[0][1] = fmaf(a0, bv.y, acc[0][1]);
            acc[0][2] = fmaf(a0, bv.z, acc[0][2]); acc[0][3] = fmaf(a0, bv.w, acc[0][3]);
            acc[1][0] = fmaf(a1, bv.x, acc[1][0]); acc[1][1] = fmaf(a1, bv.y, acc[1][1]);
            acc[1][2] = fmaf(a1, bv.z, acc[1][2]); acc[1][3] = fmaf(a1, bv.w, acc[1][3]);
            acc[2][0] = fmaf(a2, bv.x, acc[2][0]); acc[2][1] = fmaf(a2, bv.y, acc[2][1]);
            acc[2][2] = fmaf(a2, bv.z, acc[2][2]); acc[2][3] = fmaf(a2, bv.w, acc[2][3]);
            acc[3][0] = fmaf(a3, bv.x, acc[3][0]); acc[3][1] = fmaf(a3, bv.y, acc[3][1]);
            acc[3][2] = fmaf(a3, bv.z, acc[3][2]); acc[3][3] = fmaf(a3, bv.w, acc[3][3]);
        }
    }

    int tx = tid & 15, ty = tid >> 4;
    if (p.mode == 0) {
        if (ct < 4) {
            // z region: global col j in [0,256)
            #pragma unroll
            for (int r = 0; r < 4; ++r) {
                int row = row0 + ty * 4 + r;
                int j0  = ct * 64 + tx * 4;
                float4 v;
                v.x = 1.f / (1.f + __expf(-(acc[r][0] + p.bias[j0 + 0])));
                v.y = 1.f / (1.f + __expf(-(acc[r][1] + p.bias[j0 + 1])));
                v.z = 1.f / (1.f + __expf(-(acc[r][2] + p.bias[j0 + 2])));
                v.w = 1.f / (1.f + __expf(-(acc[r][3] + p.bias[j0 + 3])));
                *(float4*)&p.z[(size_t)row * 256 + j0] = v;
            }
        } else {
            // r region: global col j in [256,512), rh = sigmoid * h
            #pragma unroll
            for (int r = 0; r < 4; ++r) {
                int row = row0 + ty * 4 + r;
                int jg  = ct * 64 + tx * 4;        // 256..511 (bias index)
                int j0  = jg - 256;                // h / rh column
                float4 hv = *(const float4*)&p.h[(size_t)row * 256 + j0];
                float4 v;
                v.x = hv.x / (1.f + __expf(-(acc[r][0] + p.bias[jg + 0])));
                v.y = hv.y / (1.f + __expf(-(acc[r][1] + p.bias[jg + 1])));
                v.z = hv.z / (1.f + __expf(-(acc[r][2] + p.bias[jg + 2])));
                v.w = hv.w / (1.f + __expf(-(acc[r][3] + p.bias[jg + 3])));
                *(float4*)&p.rh[(size_t)row * 256 + j0] = v;
            }
        }
    } else {
        #pragma unroll
        for (int r = 0; r < 4; ++r) {
            int row = row0 + ty * 4 + r;
            int j0  = ct * 64 + tx * 4;
            float4 hv = *(const float4*)&p.hio[(size_t)row * 256 + j0];
            float4 zv = *(const float4*)&p.zin[(size_t)row * 256 + j0];
            float4 o;
            float c0 = tanhf(acc[r][0] + p.bias[j0 + 0]);
            float c1 = tanhf(acc[r][1] + p.bias[j0 + 1]);
            float c2 = tanhf(acc[r][2] + p.bias[j0 + 2]);
            float c3 = tanhf(acc[r][3] + p.bias[j0 + 3]);
            o.x = zv.x * hv.x + (1.f - zv.x) * c0;
            o.y = zv.y * hv.y + (1.f - zv.y) * c1;
            o.z = zv.z * hv.z + (1.f - zv.z) * c2;
            o.w = zv.w * hv.w + (1.f - zv.w) * c3;
            *(float4*)&p.hio[(size_t)row * 256 + j0] = o;
        }
    }
}

// ---------------------------------------------------------------------------
// Head: ys[b,t,n,:] = h1[b*256+n,:] @ Wout + bout     (72 blocks x 256 thr)
// ---------------------------------------------------------------------------
__global__ __launch_bounds__(256) void head_kernel(const float* __restrict__ h1,
    const float* __restrict__ Wout, const float* __restrict__ bout,
    float* __restrict__ out, int t)
{
    int g = blockIdx.x * 256 + threadIdx.x;   // 0..18431 exactly (2048*9)
    int row = g / 9;
    int o   = g - row * 9;
    if (row >= BN) return;
    const float* hr = h1 + (size_t)row * 256;
    float s = bout[o];
    for (int k = 0; k < 256; k += 4) {
        float4 hv = *(const float4*)(hr + k);
        s = fmaf(hv.x, Wout[(k + 0) * 9 + o], s);
        s = fmaf(hv.y, Wout[(k + 1) * 9 + o], s);
        s = fmaf(hv.z, Wout[(k + 2) * 9 + o], s);
        s = fmaf(hv.w, Wout[(k + 3) * 9 + o], s);
    }
    int b = row >> 8, n = row & 255;
    out[((size_t)(b * TT + t) * NN + n) * 9 + o] = s;
}

// ---------------------------------------------------------------------------
extern "C" void kernel_launch(void* const* d_in, const int* in_sizes, int n_in,
                              void* d_out, int out_size, void* d_ws, size_t ws_size,
                              hipStream_t stream) {
    const float* x2d  = (const float*)d_in[0];
    const float* mask = (const float*)d_in[1];
    const float* A    = (const float*)d_in[2];
    const float* Wx0  = (const float*)d_in[3];
    const float* Wh0  = (const float*)d_in[4];
    const float* b0   = (const float*)d_in[5];
    const float* Wx1  = (const float*)d_in[6];
    const float* Wh1  = (const float*)d_in[7];
    const float* b1   = (const float*)d_in[8];
    const float* Wout = (const float*)d_in[9];
    const float* bout = (const float*)d_in[10];
    float* out = (float*)d_out;

    float* ws = (float*)d_ws;
    const size_t SZ = (size_t)BN * HH;   // 524288 floats
    float* h0  = ws;
    float* h1  = ws + SZ;
    float* AhA = ws + 2 * SZ;
    float* AhB = ws + 3 * SZ;
    float* Ax1 = ws + 4 * SZ;
    float* z0  = ws + 5 * SZ;
    float* rh0 = ws + 6 * SZ;
    float* z1  = ws + 7 * SZ;
    float* rh1 = ws + 8 * SZ;
    float* Ax0 = ws + 9 * SZ;            // [2048][8]

    hipMemsetAsync(h0, 0, 2 * SZ * sizeof(float), stream);  // h0, h1 = 0

    for (int t = 0; t < TT; ++t) {
        // k1: Ah0 = A@h0  (+ Ax0 = A@(x_t*mask))
        { G1P p{A, h0, AhA, nullptr, nullptr, 1, 1, t, x2d, mask, Ax0};
          g1_kernel<<<dim3(160), dim3(256), 0, stream>>>(p); }
        // k2: z0, rh0
        { WAP p{AhA, Wh0, Ax0, Wx0, 6, b0, h0, z0, rh0, nullptr, nullptr, 0};
          wact_kernel<<<dim3(256), dim3(256), 0, stream>>>(p); }
        // k3: Arh0 = A@rh0
        { G1P p{A, rh0, AhA, nullptr, nullptr, 1, 0, t, x2d, mask, Ax0};
          g1_kernel<<<dim3(128), dim3(256), 0, stream>>>(p); }
        // k4: h0 update
        { WAP p{AhA, Wh0 + 512, Ax0, Wx0 + 512, 6, b0 + 512, nullptr, nullptr, nullptr, z0, h0, 1};
          wact_kernel<<<dim3(128), dim3(256), 0, stream>>>(p); }
        // k5: Ax1 = A@h0 ; Ah1 = A@h1
        { G1P p{A, h0, Ax1, h1, AhB, 2, 0, t, x2d, mask, Ax0};
          g1_kernel<<<dim3(256), dim3(256), 0, stream>>>(p); }
        // k6: z1, rh1
        { WAP p{Ax1, Wx1, AhB, Wh1, 256, b1, h1, z1, rh1, nullptr, nullptr, 0};
          wact_kernel<<<dim3(256), dim3(256), 0, stream>>>(p); }
        // k7: Arh1 = A@rh1
        { G1P p{A, rh1, AhB, nullptr, nullptr, 1, 0, t, x2d, mask, Ax0};
          g1_kernel<<<dim3(128), dim3(256), 0, stream>>>(p); }
        // k8: h1 update
        { WAP p{AhB, Wh1 + 512, Ax1, Wx1 + 512, 256, b1 + 512, nullptr, nullptr, nullptr, z1, h1, 1};
          wact_kernel<<<dim3(128), dim3(256), 0, stream>>>(p); }
        // k9: head
        head_kernel<<<dim3(72), dim3(256), 0, stream>>>(h1, Wout, bout, out, t);
    }
}

// Round 2
// 5215.331 us; speedup vs baseline: 1.8897x; 1.8897x over previous
//
#include <hip/hip_runtime.h>
#include <math.h>

#define BB 8
#define TT 64
#define NN 256
#define HH 256
#define BN 2048
#define LSTR 72   // LDS row stride in ushorts for a 64-wide K chunk

typedef float f32x4 __attribute__((ext_vector_type(4)));
typedef short s16x8 __attribute__((ext_vector_type(8)));

#define MFMA(a, b, c) __builtin_amdgcn_mfma_f32_16x16x32_bf16(a, b, c, 0, 0, 0)

__device__ __forceinline__ ushort rne_bf16(float x) {
    unsigned u = __builtin_bit_cast(unsigned, x);
    unsigned r = u + 0x7FFFu + ((u >> 16) & 1u);
    return (ushort)(r >> 16);
}
__device__ __forceinline__ float bf16_f32(ushort h) {
    unsigned u = ((unsigned)h) << 16;
    return __builtin_bit_cast(float, u);
}
__device__ __forceinline__ void split2(float x, ushort& hi, ushort& lo) {
    ushort h = rne_bf16(x);
    hi = h;
    lo = rne_bf16(x - bf16_f32(h));
}

// ---------------------------------------------------------------------------
// prep: round A to bf16; build transposed bf16 weight slabs [Ncols][256]
// ---------------------------------------------------------------------------
__global__ __launch_bounds__(256) void prep_kernel(const float* __restrict__ A,
    const float* __restrict__ Wh0, const float* __restrict__ Wx1,
    const float* __restrict__ Wh1,
    ushort* Abf, ushort* WzrT0, ushort* WcT0, ushort* WxzrT1,
    ushort* WhzrT1, ushort* WxcT1, ushort* WhcT1)
{
    int idx = blockIdx.x * 256 + threadIdx.x;
    if (idx < 65536) { Abf[idx] = rne_bf16(A[idx]); return; }
    int e = idx - 65536;
    ushort* dst; const float* src; int colOff;
    if      (e < 131072) { dst = WzrT0;  src = Wh0; colOff = 0;   }
    else if (e < 196608) { dst = WcT0;   src = Wh0; colOff = 512; e -= 131072; }
    else if (e < 327680) { dst = WxzrT1; src = Wx1; colOff = 0;   e -= 196608; }
    else if (e < 458752) { dst = WhzrT1; src = Wh1; colOff = 0;   e -= 327680; }
    else if (e < 524288) { dst = WxcT1;  src = Wx1; colOff = 512; e -= 458752; }
    else if (e < 589824) { dst = WhcT1;  src = Wh1; colOff = 512; e -= 524288; }
    else return;
    int c = e >> 8, k = e & 255;
    dst[e] = rne_bf16(src[k * 768 + colOff + c]);
}

// ---------------------------------------------------------------------------
// device helpers: exact fp32 x-job (Ax0 = A@(x_t*mask)) and head
// ---------------------------------------------------------------------------
__device__ void x_job(int lb, int tid, float* xs, float* red, const float* Af,
                      const float* x2d, const float* mask, float* Ax0, int t) {
    int b = lb >> 2, rt = lb & 3;
    const float* xbase = x2d + ((size_t)(b * TT + t) * NN) * 6;
    const float* mbase = mask + (size_t)(b * TT + t) * NN;
    {
        int m = tid;
        float mk = mbase[m];
        #pragma unroll
        for (int d = 0; d < 6; ++d) xs[m * 8 + d] = xbase[m * 6 + d] * mk;
    }
    __syncthreads();
    int i = tid & 63, q = tid >> 6;
    const float* arow = Af + (size_t)(rt * 64 + i) * 256 + q * 64;
    float a6[6] = {0.f, 0.f, 0.f, 0.f, 0.f, 0.f};
    for (int m = 0; m < 64; ++m) {
        float a = arow[m];
        const float* xv = &xs[(q * 64 + m) * 8];
        #pragma unroll
        for (int d = 0; d < 6; ++d) a6[d] = fmaf(a, xv[d], a6[d]);
    }
    #pragma unroll
    for (int d = 0; d < 6; ++d) red[(i * 4 + q) * 8 + d] = a6[d];
    __syncthreads();
    for (int idx2 = tid; idx2 < 64 * 6; idx2 += 256) {
        int ii = idx2 / 6, d = idx2 - ii * 6;
        float s = red[(ii * 4 + 0) * 8 + d] + red[(ii * 4 + 1) * 8 + d]
                + red[(ii * 4 + 2) * 8 + d] + red[(ii * 4 + 3) * 8 + d];
        Ax0[(size_t)(b * 256 + rt * 64 + ii) * 8 + d] = s;
    }
}

__device__ void head_job(int lb, int tid, const float* h1, const float* Wout,
                         const float* bout, float* out, int tprev) {
    int g = lb * 256 + tid;
    int row = g / 9, o = g - row * 9;
    if (row >= BN) return;
    const float* hr = h1 + (size_t)row * 256;
    float s = bout[o];
    for (int k = 0; k < 256; k += 4) {
        float4 hv = *(const float4*)(hr + k);
        s = fmaf(hv.x, Wout[(k + 0) * 9 + o], s);
        s = fmaf(hv.y, Wout[(k + 1) * 9 + o], s);
        s = fmaf(hv.z, Wout[(k + 2) * 9 + o], s);
        s = fmaf(hv.w, Wout[(k + 3) * 9 + o], s);
    }
    int b = row >> 8, n = row & 255;
    out[((size_t)(b * TT + tprev) * NN + n) * 9 + o] = s;
}

__global__ __launch_bounds__(256) void head_kernel(const float* __restrict__ h1,
    const float* __restrict__ Wout, const float* __restrict__ bout,
    float* __restrict__ out, int tprev)
{
    head_job(blockIdx.x, threadIdx.x, h1, Wout, bout, out, tprev);
}

// ---------------------------------------------------------------------------
// g2: A-apply via MFMA.  Y(hi/lo split, [2048][256]) = A_bf16 @ XT(hi+lo)
// Left = static A (single bf16), right = dynamic transposed split pair.
// Optional extra blocks: x-job (32) and head-job (72) for t-1.
// ---------------------------------------------------------------------------
struct G2P {
    const ushort* Abf;
    const ushort* XThi0; const ushort* XTlo0; ushort* Yhi0; ushort* Ylo0;
    const ushort* XThi1; const ushort* XTlo1; ushort* Yhi1; ushort* Ylo1;
    int nJobs;
    int withExtra;
    int t;
    const float* Af; const float* x2d; const float* mask; float* Ax0;
    const float* h1; const float* Wout; const float* bout; float* out;
};

__global__ __launch_bounds__(256) void g2_kernel(G2P p) {
    __shared__ ushort lds[3 * 64 * LSTR];
    ushort* As   = lds;
    ushort* Bshi = lds + 64 * LSTR;
    ushort* Bslo = lds + 2 * 64 * LSTR;
    const int tid = threadIdx.x;
    const int bid = blockIdx.x;
    const int mainB = p.nJobs * 128;

    if (bid < mainB) {
        const int job = bid >> 7, lb = bid & 127;
        const ushort* XThi = job ? p.XThi1 : p.XThi0;
        const ushort* XTlo = job ? p.XTlo1 : p.XTlo0;
        ushort* Yhi = job ? p.Yhi1 : p.Yhi0;
        ushort* Ylo = job ? p.Ylo1 : p.Ylo0;
        const int b = lb >> 4, rt = (lb >> 2) & 3, ct = lb & 3;

        const int lane = tid & 63, wave = tid >> 6;
        const int wr = wave >> 1, wc = wave & 1;
        const int l15 = lane & 15, q8 = (lane >> 4) << 3;

        f32x4 acc[2][2];
        acc[0][0] = 0.f; acc[0][1] = 0.f; acc[1][0] = 0.f; acc[1][1] = 0.f;

        const int rr = tid >> 2, ko = (tid & 3) << 4;
        const ushort* Asrc = p.Abf + (size_t)(rt * 64 + rr) * 256 + ko;
        const ushort* Bh   = XThi + (size_t)(b * 256 + ct * 64 + rr) * 256 + ko;
        const ushort* Bl   = XTlo + (size_t)(b * 256 + ct * 64 + rr) * 256 + ko;
        ushort* wA = &As[rr * LSTR + ko];
        ushort* wH = &Bshi[rr * LSTR + ko];
        ushort* wL = &Bslo[rr * LSTR + ko];

        for (int k0 = 0; k0 < 256; k0 += 64) {
            __syncthreads();
            *(uint4*)(wA)     = *(const uint4*)(Asrc + k0);
            *(uint4*)(wA + 8) = *(const uint4*)(Asrc + k0 + 8);
            *(uint4*)(wH)     = *(const uint4*)(Bh + k0);
            *(uint4*)(wH + 8) = *(const uint4*)(Bh + k0 + 8);
            *(uint4*)(wL)     = *(const uint4*)(Bl + k0);
            *(uint4*)(wL + 8) = *(const uint4*)(Bl + k0 + 8);
            __syncthreads();
            #pragma unroll
            for (int sub = 0; sub < 2; ++sub) {
                const int kb = sub * 32 + q8;
                s16x8 a0  = *(const s16x8*)&As[(wr * 32 + l15) * LSTR + kb];
                s16x8 a1  = *(const s16x8*)&As[(wr * 32 + 16 + l15) * LSTR + kb];
                s16x8 bh0 = *(const s16x8*)&Bshi[(wc * 32 + l15) * LSTR + kb];
                s16x8 bh1 = *(const s16x8*)&Bshi[(wc * 32 + 16 + l15) * LSTR + kb];
                s16x8 bl0 = *(const s16x8*)&Bslo[(wc * 32 + l15) * LSTR + kb];
                s16x8 bl1 = *(const s16x8*)&Bslo[(wc * 32 + 16 + l15) * LSTR + kb];
                acc[0][0] = MFMA(a0, bh0, acc[0][0]);
                acc[0][0] = MFMA(a0, bl0, acc[0][0]);
                acc[0][1] = MFMA(a0, bh1, acc[0][1]);
                acc[0][1] = MFMA(a0, bl1, acc[0][1]);
                acc[1][0] = MFMA(a1, bh0, acc[1][0]);
                acc[1][0] = MFMA(a1, bl0, acc[1][0]);
                acc[1][1] = MFMA(a1, bh1, acc[1][1]);
                acc[1][1] = MFMA(a1, bl1, acc[1][1]);
            }
        }
        const int quad = lane >> 4;
        #pragma unroll
        for (int i = 0; i < 2; ++i) {
            #pragma unroll
            for (int j = 0; j < 2; ++j) {
                const int col = ct * 64 + wc * 32 + j * 16 + l15;
                const int m0  = rt * 64 + wr * 32 + i * 16 + quad * 4;
                const size_t base = (size_t)(b * 256 + m0) * 256 + col;
                #pragma unroll
                for (int r = 0; r < 4; ++r) {
                    ushort hi, lo;
                    split2(acc[i][j][r], hi, lo);
                    Yhi[base + (size_t)r * 256] = hi;
                    Ylo[base + (size_t)r * 256] = lo;
                }
            }
        }
    } else if (bid < mainB + 32) {
        x_job(bid - mainB, tid, (float*)lds, (float*)(lds + 64 * LSTR),
              p.Af, p.x2d, p.mask, p.Ax0, p.t);
    } else {
        if (p.t > 0)
            head_job(bid - mainB - 32, tid, p.h1, p.Wout, p.bout, p.out, p.t - 1);
    }
}

// ---------------------------------------------------------------------------
// wact: gate GEMM (left = dynamic split pair, right = static bf16 WT) + epilogue
// mode 0 (zr): 8 col-tiles; ct<4 -> z=sigmoid; ct>=4 -> rhT split pair
// mode 1 (c):  4 col-tiles; h' = z*h+(1-z)*tanh(g); writes h fp32 + hT pair
// ---------------------------------------------------------------------------
struct WAP {
    const ushort* Lhi0; const ushort* Llo0; const ushort* RT0;
    const ushort* Lhi1; const ushort* Llo1; const ushort* RT1;
    int ngemm;
    const float* bias;
    int useK6; int wxColOff;
    const float* Ax0; const float* Wx0;
    const float* h;
    float* z;
    float* hOut;
    ushort* Thi; ushort* Tlo;
    int mode;
};

__global__ __launch_bounds__(256) void wact_kernel(WAP p) {
    __shared__ ushort lds[3 * 64 * LSTR];
    ushort* Ashi = lds;
    ushort* Aslo = lds + 64 * LSTR;
    ushort* Bs   = lds + 2 * 64 * LSTR;
    const int tid = threadIdx.x;
    const int bid = blockIdx.x;
    int b, rt, ct;
    if (p.mode == 0) { b = bid >> 5; rt = (bid >> 3) & 3; ct = bid & 7; }
    else             { b = bid >> 4; rt = (bid >> 2) & 3; ct = bid & 3; }

    const int lane = tid & 63, wave = tid >> 6;
    const int wr = wave >> 1, wc = wave & 1;
    const int l15 = lane & 15, q8 = (lane >> 4) << 3;

    f32x4 acc[2][2];
    acc[0][0] = 0.f; acc[0][1] = 0.f; acc[1][0] = 0.f; acc[1][1] = 0.f;

    const int rr = tid >> 2, ko = (tid & 3) << 4;
    for (int g = 0; g < p.ngemm; ++g) {
        const ushort* Lh = (g ? p.Lhi1 : p.Lhi0) + (size_t)(b * 256 + rt * 64 + rr) * 256 + ko;
        const ushort* Ll = (g ? p.Llo1 : p.Llo0) + (size_t)(b * 256 + rt * 64 + rr) * 256 + ko;
        const ushort* Rt = (g ? p.RT1  : p.RT0 ) + (size_t)(ct * 64 + rr) * 256 + ko;
        ushort* wA = &Ashi[rr * LSTR + ko];
        ushort* wL = &Aslo[rr * LSTR + ko];
        ushort* wB = &Bs[rr * LSTR + ko];
        for (int k0 = 0; k0 < 256; k0 += 64) {
            __syncthreads();
            *(uint4*)(wA)     = *(const uint4*)(Lh + k0);
            *(uint4*)(wA + 8) = *(const uint4*)(Lh + k0 + 8);
            *(uint4*)(wL)     = *(const uint4*)(Ll + k0);
            *(uint4*)(wL + 8) = *(const uint4*)(Ll + k0 + 8);
            *(uint4*)(wB)     = *(const uint4*)(Rt + k0);
            *(uint4*)(wB + 8) = *(const uint4*)(Rt + k0 + 8);
            __syncthreads();
            #pragma unroll
            for (int sub = 0; sub < 2; ++sub) {
                const int kb = sub * 32 + q8;
                s16x8 ah0 = *(const s16x8*)&Ashi[(wr * 32 + l15) * LSTR + kb];
                s16x8 ah1 = *(const s16x8*)&Ashi[(wr * 32 + 16 + l15) * LSTR + kb];
                s16x8 al0 = *(const s16x8*)&Aslo[(wr * 32 + l15) * LSTR + kb];
                s16x8 al1 = *(const s16x8*)&Aslo[(wr * 32 + 16 + l15) * LSTR + kb];
                s16x8 b0  = *(const s16x8*)&Bs[(wc * 32 + l15) * LSTR + kb];
                s16x8 b1  = *(const s16x8*)&Bs[(wc * 32 + 16 + l15) * LSTR + kb];
                acc[0][0] = MFMA(ah0, b0, acc[0][0]);
                acc[0][0] = MFMA(al0, b0, acc[0][0]);
                acc[0][1] = MFMA(ah0, b1, acc[0][1]);
                acc[0][1] = MFMA(al0, b1, acc[0][1]);
                acc[1][0] = MFMA(ah1, b0, acc[1][0]);
                acc[1][0] = MFMA(al1, b0, acc[1][0]);
                acc[1][1] = MFMA(ah1, b1, acc[1][1]);
                acc[1][1] = MFMA(al1, b1, acc[1][1]);
            }
        }
    }

    const int quad = lane >> 4;
    const int m0base = rt * 64 + wr * 32;
    int colg[2];
    #pragma unroll
    for (int j = 0; j < 2; ++j) colg[j] = ct * 64 + wc * 32 + j * 16 + l15;
    float bv[2] = { p.bias[colg[0]], p.bias[colg[1]] };
    float v[2][2][4];
    #pragma unroll
    for (int i = 0; i < 2; ++i)
        #pragma unroll
        for (int j = 0; j < 2; ++j)
            #pragma unroll
            for (int r = 0; r < 4; ++r)
                v[i][j][r] = acc[i][j][r] + bv[j];

    if (p.useK6) {
        float w6[2][6];
        #pragma unroll
        for (int j = 0; j < 2; ++j)
            #pragma unroll
            for (int d = 0; d < 6; ++d)
                w6[j][d] = p.Wx0[d * 768 + p.wxColOff + colg[j]];
        #pragma unroll
        for (int i = 0; i < 2; ++i) {
            #pragma unroll
            for (int r = 0; r < 4; ++r) {
                int row = b * 256 + m0base + i * 16 + quad * 4 + r;
                const float* ax = p.Ax0 + (size_t)row * 8;
                float a0 = ax[0], a1 = ax[1], a2 = ax[2], a3 = ax[3], a4 = ax[4], a5 = ax[5];
                #pragma unroll
                for (int j = 0; j < 2; ++j)
                    v[i][j][r] += a0 * w6[j][0] + a1 * w6[j][1] + a2 * w6[j][2]
                                + a3 * w6[j][3] + a4 * w6[j][4] + a5 * w6[j][5];
            }
        }
    }

    if (p.mode == 0) {
        if (ct < 4) {
            #pragma unroll
            for (int i = 0; i < 2; ++i)
                #pragma unroll
                for (int r = 0; r < 4; ++r) {
                    int row = b * 256 + m0base + i * 16 + quad * 4 + r;
                    #pragma unroll
                    for (int j = 0; j < 2; ++j)
                        p.z[(size_t)row * 256 + colg[j]] = 1.f / (1.f + __expf(-v[i][j][r]));
                }
        } else {
            #pragma unroll
            for (int i = 0; i < 2; ++i) {
                int m0 = m0base + i * 16 + quad * 4;
                #pragma unroll
                for (int j = 0; j < 2; ++j) {
                    int colp = colg[j] - 256;
                    ushort hi4[4], lo4[4];
                    #pragma unroll
                    for (int r = 0; r < 4; ++r) {
                        int row = b * 256 + m0 + r;
                        float s = 1.f / (1.f + __expf(-v[i][j][r]));
                        float rh = s * p.h[(size_t)row * 256 + colp];
                        split2(rh, hi4[r], lo4[r]);
                    }
                    size_t off = (size_t)b * 65536 + (size_t)colp * 256 + m0;
                    *(ushort4*)&p.Thi[off] = make_ushort4(hi4[0], hi4[1], hi4[2], hi4[3]);
                    *(ushort4*)&p.Tlo[off] = make_ushort4(lo4[0], lo4[1], lo4[2], lo4[3]);
                }
            }
        }
    } else {
        #pragma unroll
        for (int i = 0; i < 2; ++i) {
            int m0 = m0base + i * 16 + quad * 4;
            #pragma unroll
            for (int j = 0; j < 2; ++j) {
                ushort hi4[4], lo4[4];
                #pragma unroll
                for (int r = 0; r < 4; ++r) {
                    int row = b * 256 + m0 + r;
                    size_t gi = (size_t)row * 256 + colg[j];
                    float c = tanhf(v[i][j][r]);
                    float zz = p.z[gi];
                    float hh = p.h[gi];
                    float hn = zz * hh + (1.f - zz) * c;
                    p.hOut[gi] = hn;
                    split2(hn, hi4[r], lo4[r]);
                }
                size_t off = (size_t)b * 65536 + (size_t)colg[j] * 256 + m0;
                *(ushort4*)&p.Thi[off] = make_ushort4(hi4[0], hi4[1], hi4[2], hi4[3]);
                *(ushort4*)&p.Tlo[off] = make_ushort4(lo4[0], lo4[1], lo4[2], lo4[3]);
            }
        }
    }
}

// ---------------------------------------------------------------------------
extern "C" void kernel_launch(void* const* d_in, const int* in_sizes, int n_in,
                              void* d_out, int out_size, void* d_ws, size_t ws_size,
                              hipStream_t stream) {
    const float* x2d  = (const float*)d_in[0];
    const float* mask = (const float*)d_in[1];
    const float* A    = (const float*)d_in[2];
    const float* Wx0  = (const float*)d_in[3];
    const float* Wh0  = (const float*)d_in[4];
    const float* b0   = (const float*)d_in[5];
    const float* Wx1  = (const float*)d_in[6];
    const float* Wh1  = (const float*)d_in[7];
    const float* b1   = (const float*)d_in[8];
    const float* Wout = (const float*)d_in[9];
    const float* bout = (const float*)d_in[10];
    float* out = (float*)d_out;

    const size_t SZ = (size_t)BN * HH;   // 524288
    float* ws = (float*)d_ws;
    float*  h0    = ws;
    float*  h1    = h0 + SZ;
    ushort* h0Thi = (ushort*)(h1 + SZ);
    ushort* h0Tlo = h0Thi + SZ;
    ushort* h1Thi = h0Tlo + SZ;
    ushort* h1Tlo = h1Thi + SZ;
    float*  z0    = (float*)(h1Tlo + SZ);
    float*  z1    = z0 + SZ;
    float*  Ax0   = z1 + SZ;             // 16384 f
    ushort* AhAhi = (ushort*)(Ax0 + 16384);
    ushort* AhAlo = AhAhi + SZ;
    ushort* AhBhi = AhAlo + SZ;
    ushort* AhBlo = AhBhi + SZ;
    ushort* Ax1hi = AhBlo + SZ;
    ushort* Ax1lo = Ax1hi + SZ;
    ushort* rhThi = Ax1lo + SZ;
    ushort* rhTlo = rhThi + SZ;
    ushort* Abf   = rhTlo + SZ;          // 65536
    ushort* WzrT0 = Abf + 65536;         // 131072
    ushort* WcT0  = WzrT0 + 131072;      // 65536
    ushort* WxzrT1= WcT0 + 65536;        // 131072
    ushort* WhzrT1= WxzrT1 + 131072;     // 131072
    ushort* WxcT1 = WhzrT1 + 131072;     // 65536
    ushort* WhcT1 = WxcT1 + 65536;       // 65536

    // zero h0,h1 (fp32) and the four transposed split buffers (bf16 zero = 0)
    hipMemsetAsync(h0, 0, (2 * SZ) * sizeof(float) + 4 * SZ * sizeof(ushort), stream);

    prep_kernel<<<dim3(2560), dim3(256), 0, stream>>>(A, Wh0, Wx1, Wh1,
        Abf, WzrT0, WcT0, WxzrT1, WhzrT1, WxcT1, WhcT1);

    for (int t = 0; t < TT; ++t) {
        // k1: Ah0 = A@h0, Ah1 = A@h1, Ax0 (exact), head(t-1)
        { G2P p{Abf, h0Thi, h0Tlo, AhAhi, AhAlo, h1Thi, h1Tlo, AhBhi, AhBlo,
                2, 1, t, A, x2d, mask, Ax0, h1, Wout, bout, out};
          g2_kernel<<<dim3(360), dim3(256), 0, stream>>>(p); }
        // k2: z0, rh0T
        { WAP p{AhAhi, AhAlo, WzrT0, nullptr, nullptr, nullptr, 1,
                b0, 1, 0, Ax0, Wx0, h0, z0, nullptr, rhThi, rhTlo, 0};
          wact_kernel<<<dim3(256), dim3(256), 0, stream>>>(p); }
        // k3: Arh0 = A@rh0T
        { G2P p{Abf, rhThi, rhTlo, AhAhi, AhAlo, nullptr, nullptr, nullptr, nullptr,
                1, 0, t, A, x2d, mask, Ax0, h1, Wout, bout, out};
          g2_kernel<<<dim3(128), dim3(256), 0, stream>>>(p); }
        // k4: h0 update (+ h0T)
        { WAP p{AhAhi, AhAlo, WcT0, nullptr, nullptr, nullptr, 1,
                b0 + 512, 1, 512, Ax0, Wx0, h0, z0, h0, h0Thi, h0Tlo, 1};
          wact_kernel<<<dim3(128), dim3(256), 0, stream>>>(p); }
        // k5: Ax1 = A@h0T
        { G2P p{Abf, h0Thi, h0Tlo, Ax1hi, Ax1lo, nullptr, nullptr, nullptr, nullptr,
                1, 0, t, A, x2d, mask, Ax0, h1, Wout, bout, out};
          g2_kernel<<<dim3(128), dim3(256), 0, stream>>>(p); }
        // k6: z1, rh1T  (Ax1@Wx1zr + Ah1@Wh1zr)
        { WAP p{Ax1hi, Ax1lo, WxzrT1, AhBhi, AhBlo, WhzrT1, 2,
                b1, 0, 0, Ax0, Wx0, h1, z1, nullptr, rhThi, rhTlo, 0};
          wact_kernel<<<dim3(256), dim3(256), 0, stream>>>(p); }
        // k7: Arh1 = A@rh1T
        { G2P p{Abf, rhThi, rhTlo, AhBhi, AhBlo, nullptr, nullptr, nullptr, nullptr,
                1, 0, t, A, x2d, mask, Ax0, h1, Wout, bout, out};
          g2_kernel<<<dim3(128), dim3(256), 0, stream>>>(p); }
        // k8: h1 update (+ h1T)  (Arh1@Wh1c + Ax1@Wx1c)
        { WAP p{AhBhi, AhBlo, WhcT1, Ax1hi, Ax1lo, WxcT1, 2,
                b1 + 512, 0, 0, Ax0, Wx0, h1, z1, h1, h1Thi, h1Tlo, 1};
          wact_kernel<<<dim3(128), dim3(256), 0, stream>>>(p); }
    }
    // final head for t = 63
    head_kernel<<<dim3(72), dim3(256), 0, stream>>>(h1, Wout, bout, out, TT - 1);
}